// Round 1
// 1176.125 us; speedup vs baseline: 1.0682x; 1.0682x over previous
//
#include <hip/hip_runtime.h>
#include <math.h>
#include <stdint.h>

#define BB 8
#define CC 128
#define HH 256
#define WW 256
#define PLANE (HH * WW)
#define YSTR 68  // padded fp32 row stride for y buffer (68*4=272B, 16B aligned, banks spread)

typedef __attribute__((ext_vector_type(8))) short short8;
typedef __attribute__((ext_vector_type(4))) float f32x4;
typedef __attribute__((ext_vector_type(2))) int i32x2;

__device__ __forceinline__ unsigned short f2bf(float f) {
  unsigned u = __float_as_uint(f);
  u += 0x7FFFu + ((u >> 16) & 1u);  // RNE
  return (unsigned short)(u >> 16);
}
__device__ __forceinline__ float bf2f(unsigned short h) {
  return __uint_as_float(((unsigned)h) << 16);
}

// gfx950 LDS transpose read: lane l, elem j reads lds[(l&15) + j*16 + (l>>4)*64] (bf16 elems)
// given per-lane byte addr = base + (l&15)*2 + (l>>4)*128; instr gathers j at +j*32B.
__device__ __forceinline__ i32x2 tr16(uint32_t addr) {
  i32x2 d;
  asm volatile("ds_read_b64_tr_b16 %0, %1" : "=v"(d) : "v"(addr));
  return d;
}
__device__ __forceinline__ short8 mk8(i32x2 a, i32x2 b) {
  union { i32x2 d[2]; short8 s; } u;
  u.d[0] = a; u.d[1] = b;
  return u.s;
}

// ---------------------------------------------------------------------------
// Prep: kkt (8x8 circular-conv taps, channel-fastest), bf16 hi/lo splits of
// w_in [o][c] and w_before [o][c] (MFMA A-operands, contiguous k), w_out_t.
// ---------------------------------------------------------------------------
__global__ __launch_bounds__(256) void prep_kernel(
    const float* __restrict__ filt, const float* __restrict__ w_in,
    const float* __restrict__ w_before, const float* __restrict__ w_out,
    float* __restrict__ kkt, unsigned short* __restrict__ w_in_h,
    unsigned short* __restrict__ w_in_l,
    unsigned short* __restrict__ w_before_h,
    unsigned short* __restrict__ w_before_l, float* __restrict__ w_out_t) {
  int idx = blockIdx.x * 256 + threadIdx.x;
  if (idx < 8192) {
    int c = idx >> 6;
    int un = idx & 63;
    int u = un >> 3, n = un & 7;
    const float cs8[8] = {1.f,  0.70710678118654752f,  0.f, -0.70710678118654752f,
                          -1.f, -0.70710678118654752f, 0.f, 0.70710678118654752f};
    float s = 0.f;
#pragma unroll
    for (int p = 0; p < 8; ++p) {
#pragma unroll
      for (int q = 0; q < 5; ++q) {
        float m = (q == 0 || q == 4) ? 1.f : 2.f;
        s += m * filt[(c * 8 + p) * 5 + q] * cs8[(p * u + q * n) & 7];
      }
    }
    kkt[un * 128 + c] = s * (1.f / 64.f);
  } else if (idx < 24576) {
    int j = idx - 8192;  // o*128+c
    float f = w_in[j];
    unsigned short h = f2bf(f);
    w_in_h[j] = h;
    w_in_l[j] = f2bf(f - bf2f(h));
  } else if (idx < 28672) {
    int j = idx - 24576;  // o*64+c
    float f = w_before[j];
    unsigned short h = f2bf(f);
    w_before_h[j] = h;
    w_before_l[j] = f2bf(f - bf2f(h));
  } else if (idx < 36864) {
    int j = idx - 28672;
    int o = j >> 6, c = j & 63;
    w_out_t[c * 128 + o] = w_out[o * 64 + c];
  }
}

// ---------------------------------------------------------------------------
// Fused: w_in mix (MFMA bf16 hi/lo split) -> 8x8 circular conv (VALU, LDS row
// reads) -> exact GeGLU -> w_before mix (MFMA) -> g2.
// One block per 8x8 patch, 256 threads = 4 waves.
// LDS map (51200 B):
//   [0,16384)      X_hi bf16, subtiled for tr16 B-frags   \ aliased later by
//   [16384,32768)  X_lo bf16                              /  y fp32 [128][YSTR]
//   [0,34816)      y fp32 (after stage A)
//   [34816,43008)  G_hi bf16 subtiled   [43008,51200) G_lo
// Subtile layout (X, 128c x 64px): elem addr =
//   ((kstep*4+nt)*2+blk)*256 + (g*4+j)*16 + col
//   kstep=c>>5, w=c&31, blk=(w>>2)&1, g=w>>3, j=w&3, nt=px>>4, col=px&15
// so tr16 at blk0/blk1 yields lane's k-slice c = (l>>4)*8 + 0..7.  G: same
// with 2 ksteps (64 c).
// ---------------------------------------------------------------------------
__global__ __launch_bounds__(256) void fused1_kernel(
    const float* __restrict__ x, const unsigned short* __restrict__ w_in_h,
    const unsigned short* __restrict__ w_in_l,
    const unsigned short* __restrict__ w_before_h,
    const unsigned short* __restrict__ w_before_l,
    const float* __restrict__ kkt, float* __restrict__ g2) {
  __shared__ __align__(16) char smem[51200];
  unsigned short* xh = (unsigned short*)smem;
  unsigned short* xl = (unsigned short*)(smem + 16384);
  float* yb = (float*)smem;
  unsigned short* gh = (unsigned short*)(smem + 34816);
  unsigned short* gl = (unsigned short*)(smem + 43008);

  int bid = blockIdx.x;
  int b = bid >> 10;
  int py = (bid >> 5) & 31;
  int pxb = bid & 31;
  int h0 = py * 8, w0 = pxb * 8;
  int t = threadIdx.x;
  const float* xb = x + (size_t)b * CC * PLANE;

  // ---- stage X: global fp32 -> bf16 hi/lo, subtiled LDS ----
#pragma unroll
  for (int it = 0; it < 4; ++it) {
    int oc = t + it * 256;  // 0..1023 = 128c x 8 rows
    int c = oc >> 3, ph = oc & 7;
    const float* src = xb + (size_t)c * PLANE + (size_t)(h0 + ph) * WW + w0;
    float4 v0 = *(const float4*)src;
    float4 v1 = *(const float4*)(src + 4);
    float v[8] = {v0.x, v0.y, v0.z, v0.w, v1.x, v1.y, v1.z, v1.w};
    unsigned hu[4], lu[4];
#pragma unroll
    for (int q = 0; q < 4; ++q) {
      unsigned short ha = f2bf(v[2 * q]), hb = f2bf(v[2 * q + 1]);
      unsigned short la = f2bf(v[2 * q] - bf2f(ha));
      unsigned short lb = f2bf(v[2 * q + 1] - bf2f(hb));
      hu[q] = (unsigned)ha | ((unsigned)hb << 16);
      lu[q] = (unsigned)la | ((unsigned)lb << 16);
    }
    int ks = c >> 5, wc = c & 31;
    int blk = (wc >> 2) & 1, sg = wc >> 3, jj = wc & 3;
    int nt = ph >> 1, colh = ph & 1;
    int e = ((ks * 4 + nt) * 2 + blk) * 256 + (sg * 4 + jj) * 16 + colh * 8;
    *(uint4*)(xh + e) = make_uint4(hu[0], hu[1], hu[2], hu[3]);
    *(uint4*)(xl + e) = make_uint4(lu[0], lu[1], lu[2], lu[3]);
  }
  __syncthreads();

  // ---- stage A: y[o][px] = sum_c w_in[o,c]*x[c,px] via MFMA, split bf16 ----
  int l = t & 63;
  int wv = t >> 6;  // wave id: owns o in [wv*32, wv*32+32)
  int l15 = l & 15, l4 = l >> 4;
  uint32_t trbase =
      (uint32_t)(uintptr_t)smem + (uint32_t)(l15 * 2 + l4 * 128);

  f32x4 zero4 = {0.f, 0.f, 0.f, 0.f};
  f32x4 acc[2][4];
#pragma unroll
  for (int mt = 0; mt < 2; ++mt)
#pragma unroll
    for (int nt = 0; nt < 4; ++nt) acc[mt][nt] = zero4;

#pragma unroll
  for (int ks = 0; ks < 4; ++ks) {
    short8 ah[2], al[2];
#pragma unroll
    for (int mt = 0; mt < 2; ++mt) {
      int o = wv * 32 + mt * 16 + l15;
      ah[mt] = *(const short8*)(w_in_h + o * 128 + ks * 32 + l4 * 8);
      al[mt] = *(const short8*)(w_in_l + o * 128 + ks * 32 + l4 * 8);
    }
#pragma unroll
    for (int nt = 0; nt < 4; ++nt) {
      uint32_t base = trbase + (uint32_t)((ks * 4 + nt) * 1024);
      i32x2 h0v = tr16(base);
      i32x2 h1v = tr16(base + 512);
      i32x2 l0v = tr16(base + 16384);
      i32x2 l1v = tr16(base + 16384 + 512);
      asm volatile("s_waitcnt lgkmcnt(0)" ::: "memory");
      __builtin_amdgcn_sched_barrier(0);
      short8 bh = mk8(h0v, h1v);
      short8 bl = mk8(l0v, l1v);
#pragma unroll
      for (int mt = 0; mt < 2; ++mt) {
        acc[mt][nt] = __builtin_amdgcn_mfma_f32_16x16x32_bf16(
            ah[mt], bh, acc[mt][nt], 0, 0, 0);
        acc[mt][nt] = __builtin_amdgcn_mfma_f32_16x16x32_bf16(
            ah[mt], bl, acc[mt][nt], 0, 0, 0);
        acc[mt][nt] = __builtin_amdgcn_mfma_f32_16x16x32_bf16(
            al[mt], bh, acc[mt][nt], 0, 0, 0);
      }
    }
  }
  __syncthreads();  // X staging dead; safe to overwrite with y

  // D layout: col px = nt*16 + l15, row o = wv*32 + mt*16 + l4*4 + r
#pragma unroll
  for (int mt = 0; mt < 2; ++mt)
#pragma unroll
    for (int nt = 0; nt < 4; ++nt)
#pragma unroll
      for (int r = 0; r < 4; ++r) {
        int o = wv * 32 + mt * 16 + l4 * 4 + r;
        yb[o * YSTR + nt * 16 + l15] = acc[mt][nt][r];
      }
  __syncthreads();

  // ---- stage B: per-channel 8x8 circular conv (rows from LDS, reg rotate) ----
  int ob = t >> 3;  // 4 channels ob*4..+3
  int pb = t & 7;   // output row
  float acc2[4][8];
#pragma unroll
  for (int i = 0; i < 4; ++i)
#pragma unroll
    for (int j = 0; j < 8; ++j) acc2[i][j] = 0.f;

#pragma unroll
  for (int s = 0; s < 8; ++s) {
    int r = (pb - s) & 7;
    float yr[4][8];
#pragma unroll
    for (int i = 0; i < 4; ++i) {
      const float* p = yb + (ob * 4 + i) * YSTR + r * 8;
      float4 v0 = *(const float4*)p;
      float4 v1 = *(const float4*)(p + 4);
      yr[i][0] = v0.x; yr[i][1] = v0.y; yr[i][2] = v0.z; yr[i][3] = v0.w;
      yr[i][4] = v1.x; yr[i][5] = v1.y; yr[i][6] = v1.z; yr[i][7] = v1.w;
    }
#pragma unroll
    for (int tt = 0; tt < 8; ++tt) {
      float4 kv = *(const float4*)(kkt + (s * 8 + tt) * 128 + ob * 4);
      float ka[4] = {kv.x, kv.y, kv.z, kv.w};
#pragma unroll
      for (int i = 0; i < 4; ++i)
#pragma unroll
        for (int j = 0; j < 8; ++j)
          acc2[i][j] += ka[i] * yr[i][(j - tt) & 7];
    }
  }
  __syncthreads();  // all conv reads of y complete before overwrite

#pragma unroll
  for (int i = 0; i < 4; ++i) {
    float* dst = yb + (ob * 4 + i) * YSTR + pb * 8;
    *(float4*)dst = make_float4(acc2[i][0], acc2[i][1], acc2[i][2], acc2[i][3]);
    *(float4*)(dst + 4) =
        make_float4(acc2[i][4], acc2[i][5], acc2[i][6], acc2[i][7]);
  }
  __syncthreads();

  // ---- stage C: GeGLU, convert to bf16 hi/lo, pack into G subtiles ----
#pragma unroll
  for (int it = 0; it < 2; ++it) {
    int oc = t + it * 256;  // 0..511 = 64c x 8 rows
    int c = oc >> 3, ocl = oc & 7;
    const float* pa = yb + c * YSTR + ocl * 8;
    const float* pg = yb + (c + 64) * YSTR + ocl * 8;
    float4 a0 = *(const float4*)pa, a1 = *(const float4*)(pa + 4);
    float4 g0 = *(const float4*)pg, g1 = *(const float4*)(pg + 4);
    float av[8] = {a0.x, a0.y, a0.z, a0.w, a1.x, a1.y, a1.z, a1.w};
    float gv[8] = {g0.x, g0.y, g0.z, g0.w, g1.x, g1.y, g1.z, g1.w};
    unsigned hu[4], lu[4];
#pragma unroll
    for (int q = 0; q < 4; ++q) {
      float r0, r1;
      {
        float a = av[2 * q];
        r0 = 0.5f * a * (1.f + erff(a * 0.70710678118654752f)) * gv[2 * q];
      }
      {
        float a = av[2 * q + 1];
        r1 = 0.5f * a * (1.f + erff(a * 0.70710678118654752f)) * gv[2 * q + 1];
      }
      unsigned short ha = f2bf(r0), hb = f2bf(r1);
      unsigned short la = f2bf(r0 - bf2f(ha)), lb = f2bf(r1 - bf2f(hb));
      hu[q] = (unsigned)ha | ((unsigned)hb << 16);
      lu[q] = (unsigned)la | ((unsigned)lb << 16);
    }
    int ks = c >> 5, wc = c & 31;
    int blk = (wc >> 2) & 1, sg = wc >> 3, jj = wc & 3;
    int nt = ocl >> 1, colh = ocl & 1;
    int e = ((ks * 4 + nt) * 2 + blk) * 256 + (sg * 4 + jj) * 16 + colh * 8;
    *(uint4*)(gh + e) = make_uint4(hu[0], hu[1], hu[2], hu[3]);
    *(uint4*)(gl + e) = make_uint4(lu[0], lu[1], lu[2], lu[3]);
  }
  __syncthreads();

  // ---- stage D: g2[o'] = sum_c w_before[o',c]*g[c] via MFMA, split bf16 ----
  f32x4 accd[4];
#pragma unroll
  for (int nt = 0; nt < 4; ++nt) accd[nt] = zero4;

  uint32_t gtrbase = (uint32_t)(uintptr_t)smem + 34816u +
                     (uint32_t)(l15 * 2 + l4 * 128);
#pragma unroll
  for (int ks = 0; ks < 2; ++ks) {
    int o = wv * 16 + l15;  // wave owns o' tile [wv*16, wv*16+16)
    short8 wbh = *(const short8*)(w_before_h + o * 64 + ks * 32 + l4 * 8);
    short8 wbl = *(const short8*)(w_before_l + o * 64 + ks * 32 + l4 * 8);
#pragma unroll
    for (int nt = 0; nt < 4; ++nt) {
      uint32_t base = gtrbase + (uint32_t)((ks * 4 + nt) * 1024);
      i32x2 h0v = tr16(base);
      i32x2 h1v = tr16(base + 512);
      i32x2 l0v = tr16(base + 8192);
      i32x2 l1v = tr16(base + 8192 + 512);
      asm volatile("s_waitcnt lgkmcnt(0)" ::: "memory");
      __builtin_amdgcn_sched_barrier(0);
      short8 bh = mk8(h0v, h1v);
      short8 bl = mk8(l0v, l1v);
      accd[nt] =
          __builtin_amdgcn_mfma_f32_16x16x32_bf16(wbh, bh, accd[nt], 0, 0, 0);
      accd[nt] =
          __builtin_amdgcn_mfma_f32_16x16x32_bf16(wbh, bl, accd[nt], 0, 0, 0);
      accd[nt] =
          __builtin_amdgcn_mfma_f32_16x16x32_bf16(wbl, bh, accd[nt], 0, 0, 0);
    }
  }
  // yb (y2) is dead after GeGLU barrier; stage result there for coalesced out
#pragma unroll
  for (int nt = 0; nt < 4; ++nt)
#pragma unroll
    for (int r = 0; r < 4; ++r) {
      int o = wv * 16 + l4 * 4 + r;
      yb[o * YSTR + nt * 16 + l15] = accd[nt][r];
    }
  __syncthreads();

#pragma unroll
  for (int it = 0; it < 2; ++it) {
    int oc = t + it * 256;
    int o = oc >> 3, ocl = oc & 7;
    const float* p = yb + o * YSTR + ocl * 8;
    float4 v0 = *(const float4*)p;
    float4 v1 = *(const float4*)(p + 4);
    float* dst = g2 + (size_t)b * 64 * PLANE + (size_t)o * PLANE +
                 (size_t)(h0 + ocl) * WW + w0;
    *(float4*)dst = v0;
    *(float4*)(dst + 4) = v1;
  }
}

// ---------------------------------------------------------------------------
// Depthwise 3x3, SAME.  Block: 32 rows x 64 cols of one (b,c) plane.
// ---------------------------------------------------------------------------
__global__ __launch_bounds__(256) void dwconv_kernel(
    const float* __restrict__ g2, const float* __restrict__ w_dw,
    float* __restrict__ dout) {
  int wseg = blockIdx.x;
  int hseg = blockIdx.y;
  int bc = blockIdx.z;
  int c = bc & 63;
  const float* src = g2 + (size_t)bc * PLANE;
  float* dst = dout + (size_t)bc * PLANE;
  __shared__ float tile[34][66];
  int w0 = wseg * 64, h0 = hseg * 32;
  int t = threadIdx.x;
  for (int f = t; f < 34 * 66; f += 256) {
    int r = f / 66, cl = f - r * 66;
    int hh = h0 + r - 1, ww = w0 + cl - 1;
    float v = 0.f;
    if (hh >= 0 && hh < HH && ww >= 0 && ww < WW) v = src[hh * WW + ww];
    tile[r][cl] = v;
  }
  float k9[9];
#pragma unroll
  for (int i = 0; i < 9; ++i) k9[i] = w_dw[c * 9 + i];
  __syncthreads();
  int cl = t & 63;
#pragma unroll
  for (int rep = 0; rep < 8; ++rep) {
    int r = rep * 4 + (t >> 6);
    float s = 0.f;
#pragma unroll
    for (int i = 0; i < 3; ++i)
#pragma unroll
      for (int j = 0; j < 3; ++j) s += k9[i * 3 + j] * tile[r + i][cl + j];
    dst[(size_t)(h0 + r) * WW + w0 + cl] = s;
  }
}

// ---------------------------------------------------------------------------
// out = w_out @ d + x.
// ---------------------------------------------------------------------------
__global__ __launch_bounds__(256) void mixout_kernel(
    const float* __restrict__ d, const float* __restrict__ w_out_t,
    const float* __restrict__ x, float* __restrict__ out) {
  int bid = blockIdx.x;
  int wseg = bid & 3;
  int hh = (bid >> 2) & 255;
  int b = bid >> 10;
  __shared__ float ds[64 * 64];
  int t = threadIdx.x;
  const float* dbase = d + (size_t)b * 64 * PLANE + (size_t)hh * WW + wseg * 64;
#pragma unroll
  for (int i = 0; i < 4; ++i) {
    int f = t + 256 * i;
    int c = f >> 4, k4 = f & 15;
    *(float4*)(ds + c * 64 + k4 * 4) =
        *(const float4*)(dbase + (size_t)c * PLANE + k4 * 4);
  }
  __syncthreads();

  int og = __builtin_amdgcn_readfirstlane(t >> 6);
  int pix = t & 63;
  float acc[32];
#pragma unroll
  for (int i = 0; i < 32; ++i) acc[i] = 0.f;

  const float* wt = w_out_t + og * 32;
#pragma unroll 2
  for (int c = 0; c < 64; ++c) {
    float xv = ds[c * 64 + pix];
#pragma unroll
    for (int i = 0; i < 32; ++i) acc[i] += wt[c * 128 + i] * xv;
  }

  size_t pbase =
      (size_t)b * CC * PLANE + (size_t)hh * WW + (size_t)wseg * 64 + pix;
#pragma unroll
  for (int i = 0; i < 32; ++i) {
    int o = og * 32 + i;
    out[pbase + (size_t)o * PLANE] = acc[i] + x[pbase + (size_t)o * PLANE];
  }
}

extern "C" void kernel_launch(void* const* d_in, const int* in_sizes, int n_in,
                              void* d_out, int out_size, void* d_ws,
                              size_t ws_size, hipStream_t stream) {
  const float* x = (const float*)d_in[0];
  const float* fft_filt = (const float*)d_in[1];
  const float* w_in = (const float*)d_in[2];
  const float* w_before = (const float*)d_in[3];
  const float* w_dw = (const float*)d_in[4];
  const float* w_out = (const float*)d_in[5];
  float* out = (float*)d_out;

  char* ws = (char*)d_ws;
  float* kkt = (float*)ws;                                      // 8192 f
  float* w_out_t = kkt + 8192;                                  // 8192 f
  unsigned short* w_in_h = (unsigned short*)(w_out_t + 8192);   // 16384 bf16
  unsigned short* w_in_l = w_in_h + 16384;                      // 16384 bf16
  unsigned short* w_before_h = w_in_l + 16384;                  // 4096 bf16
  unsigned short* w_before_l = w_before_h + 4096;               // 4096 bf16
  float* g2 = (float*)(ws + (1 << 20));                         // 128 MB
  float* dbuf = g2 + (size_t)BB * 64 * PLANE;                   // 128 MB

  hipLaunchKernelGGL(prep_kernel, dim3(144), dim3(256), 0, stream, fft_filt,
                     w_in, w_before, w_out, kkt, w_in_h, w_in_l, w_before_h,
                     w_before_l, w_out_t);
  hipLaunchKernelGGL(fused1_kernel, dim3(8192), dim3(256), 0, stream, x,
                     w_in_h, w_in_l, w_before_h, w_before_l, kkt, g2);
  hipLaunchKernelGGL(dwconv_kernel, dim3(4, 8, 512), dim3(256), 0, stream, g2,
                     w_dw, dbuf);
  hipLaunchKernelGGL(mixout_kernel, dim3(8192), dim3(256), 0, stream, dbuf,
                     w_out_t, x, out);
}